// Round 2
// baseline (846.106 us; speedup 1.0000x reference)
//
#include <hip/hip_runtime.h>
#include <cstdint>
#include <cstddef>

// Problem constants (reference: N=16384, DX1=DX2=1024, DH=2048)
#define NR 16384
#define DX 1024
#define DH 2048

typedef unsigned short u16;
typedef _Float16 half8 __attribute__((ext_vector_type(8)));
typedef _Float16 half4v __attribute__((ext_vector_type(4)));
typedef float f32x16 __attribute__((ext_vector_type(16)));

__device__ __forceinline__ u16 f2h_bits(float v) {
    union { _Float16 h; u16 u; } c;
    c.h = (_Float16)v;
    return c.u;
}

// async global->LDS, 16B per lane; LDS dest = wave-uniform base + lane*16
__device__ __forceinline__ void gl_lds16(const void* g, void* l) {
    __builtin_amdgcn_global_load_lds(
        (const __attribute__((address_space(1))) void*)g,
        (__attribute__((address_space(3))) void*)l, 16, 0, 0);
}

// ---------------------------------------------------------------------------
// fp32 -> fp16 elementwise cast (vectorized float4 -> half4). n must be %1024.
__global__ __launch_bounds__(256) void cast_f32_f16(const float* __restrict__ in,
                                                    u16* __restrict__ out) {
    size_t i = ((size_t)blockIdx.x * 256 + threadIdx.x) * 4;
    float4 v = *(const float4*)&in[i];
    half4v o = { (_Float16)v.x, (_Float16)v.y, (_Float16)v.z, (_Float16)v.w };
    *(half4v*)&out[i] = o;
}

// ---------------------------------------------------------------------------
// W [K,D] fp32 -> Wt [D,K] fp16 (LDS tiled transpose). K,D % 32 == 0.
__global__ __launch_bounds__(256) void transpose_cast(const float* __restrict__ in,
                                                      u16* __restrict__ out,
                                                      int K, int D) {
    __shared__ float tile[32][33];
    int tx = threadIdx.x & 31;
    int ty = threadIdx.x >> 5;                  // 0..7
    int d0 = blockIdx.x * 32, k0 = blockIdx.y * 32;
#pragma unroll
    for (int i = 0; i < 32; i += 8)
        tile[ty + i][tx] = in[(size_t)(k0 + ty + i) * D + d0 + tx];
    __syncthreads();
#pragma unroll
    for (int i = 0; i < 32; i += 8)
        out[(size_t)(d0 + ty + i) * K + k0 + tx] = f2h_bits(tile[tx][ty + i]);
}

// ---------------------------------------------------------------------------
// 128x128-tile GEMM, BK=64, 256 threads (4 waves 2x2), 32x32x16 f16 MFMA.
// A [M,K] fp16 row-major, Bt [N,K] fp16 row-major (i.e. B transposed).
// LDS is stored in "chunk" layout: chunk (rt, ks) holds, at lane L's slot
// (chunk*1024B + L*16B), the 8 halfs A[rt*32 + (L&31)][ks*16 + (L>>5)*8 ..+8].
// This is exactly the 32x32x16 MFMA A/B fragment pattern, so every
// fragment load is ds_read_b128 at (uniform + lane*16): conflict-free.
// Grid: blockIdx.x = N-tile (few, consecutive blocks share the A slab in L2),
//       blockIdx.y = M-tile.
// MODE 0: C[M,N] = A@B + bias   (fp16 out)
// MODE 1: Lacc[row] += sum_col (A@B + bias - Xref)^2   (atomic per row)
template <int MODE>
__global__ __launch_bounds__(256) void gemm_bt(
    const u16* __restrict__ A, const u16* __restrict__ Bt,
    const float* __restrict__ bias,
    u16* __restrict__ C, const float* __restrict__ Xref,
    float* __restrict__ Lacc,
    int M, int N, int K) {
    __shared__ __align__(16) u16 As[128 * 64];   // 16 KB
    __shared__ __align__(16) u16 Bs[128 * 64];   // 16 KB

    const int tid  = threadIdx.x;
    const int lane = tid & 63;
    const int w    = tid >> 6;
    const int wr   = w >> 1, wc = w & 1;
    const int n0 = blockIdx.x * 128, m0 = blockIdx.y * 128;
    const int l31 = lane & 31, h = lane >> 5;

    f32x16 acc[2][2] = {};

    // staging: 32 chunks of 1KB per BK=64 iter; wave w stages chunks w*8..w*8+7
    const u16* gsrc[8];
    u16* ldst[8];
#pragma unroll
    for (int cc = 0; cc < 8; ++cc) {
        int c = w * 8 + cc;                     // wave-uniform
        int rt = (c >> 2) & 3, ks = c & 3;
        int row = rt * 32 + l31;
        int ko  = ks * 16 + h * 8;
        if (c < 16) {
            gsrc[cc] = A + (size_t)(m0 + row) * K + ko;
            ldst[cc] = &As[(rt * 4 + ks) * 512];
        } else {
            gsrc[cc] = Bt + (size_t)(n0 + row) * K + ko;
            ldst[cc] = &Bs[(rt * 4 + ks) * 512];
        }
    }

    for (int kt = 0; kt < K; kt += 64) {
#pragma unroll
        for (int cc = 0; cc < 8; ++cc)
            gl_lds16(gsrc[cc] + kt, ldst[cc]);
        __syncthreads();   // drain vmcnt(0) once per 64-wide K slab

#pragma unroll
        for (int ks = 0; ks < 4; ++ks) {
            half8 af[2], bf[2];
#pragma unroll
            for (int i = 0; i < 2; ++i) {
                af[i] = *(const half8*)&As[((wr * 2 + i) * 4 + ks) * 512 + lane * 8];
                bf[i] = *(const half8*)&Bs[((wc * 2 + i) * 4 + ks) * 512 + lane * 8];
            }
#pragma unroll
            for (int i = 0; i < 2; ++i)
#pragma unroll
                for (int j = 0; j < 2; ++j)
                    acc[i][j] = __builtin_amdgcn_mfma_f32_32x32x16_f16(
                        af[i], bf[j], acc[i][j], 0, 0, 0);
        }
        __syncthreads();
    }

    // epilogue: 32x32 C/D layout col = lane&31, row = (r&3) + 8*(r>>2) + 4*h
    const int colb = n0 + wc * 64 + l31;
    float bj0 = bias[colb], bj1 = bias[colb + 32];

    if (MODE == 0) {
#pragma unroll
        for (int i = 0; i < 2; ++i) {
            int rowb = m0 + wr * 64 + i * 32 + 4 * h;
#pragma unroll
            for (int r = 0; r < 16; ++r) {
                int row = rowb + (r & 3) + 8 * (r >> 2);
                size_t ro = (size_t)row * N + colb;
                C[ro]      = f2h_bits(acc[i][0][r] + bj0);
                C[ro + 32] = f2h_bits(acc[i][1][r] + bj1);
            }
        }
    } else {
#pragma unroll
        for (int i = 0; i < 2; ++i) {
            int rowb = m0 + wr * 64 + i * 32 + 4 * h;
#pragma unroll
            for (int r = 0; r < 16; ++r) {
                int row = rowb + (r & 3) + 8 * (r >> 2);
                size_t ro = (size_t)row * N + colb;
                float d0 = acc[i][0][r] + bj0 - Xref[ro];
                float d1 = acc[i][1][r] + bj1 - Xref[ro + 32];
                float s = d0 * d0 + d1 * d1;
                // reduce over the 32 lanes (cols) sharing this row
                s += __shfl_xor(s, 1, 64);
                s += __shfl_xor(s, 2, 64);
                s += __shfl_xor(s, 4, 64);
                s += __shfl_xor(s, 8, 64);
                s += __shfl_xor(s, 16, 64);
                if (l31 == 0) atomicAdd(&Lacc[row], s);
            }
        }
    }
}

// ---------------------------------------------------------------------------
// Per-row L3 = sum (h1-h2)^2 and L4row = sum (h1+h2)*whoW. One block per row.
__global__ __launch_bounds__(256) void l34_kernel(
    const u16* __restrict__ H1, const u16* __restrict__ H2,
    const float* __restrict__ whoW,
    float* __restrict__ L3, float* __restrict__ L4) {
    int row = blockIdx.x;
    int tid = threadIdx.x;
    const half8 h1 = *(const half8*)&H1[(size_t)row * DH + tid * 8];
    const half8 h2 = *(const half8*)&H2[(size_t)row * DH + tid * 8];
    float4 w0 = *(const float4*)&whoW[tid * 8];
    float4 w1 = *(const float4*)&whoW[tid * 8 + 4];
    float wv[8] = { w0.x, w0.y, w0.z, w0.w, w1.x, w1.y, w1.z, w1.w };
    float s3 = 0.f, s4 = 0.f;
#pragma unroll
    for (int u = 0; u < 8; ++u) {
        float a = (float)h1[u], b = (float)h2[u];
        float d = a - b;
        s3 += d * d;
        s4 += (a + b) * wv[u];
    }
#pragma unroll
    for (int off = 1; off < 64; off <<= 1) {
        s3 += __shfl_xor(s3, off, 64);
        s4 += __shfl_xor(s4, off, 64);
    }
    __shared__ float sm[8];
    int wvi = tid >> 6, ln = tid & 63;
    if (ln == 0) { sm[wvi] = s3; sm[4 + wvi] = s4; }
    __syncthreads();
    if (tid == 0) {
        L3[row] = sm[0] + sm[1] + sm[2] + sm[3];
        L4[row] = sm[4] + sm[5] + sm[6] + sm[7];
    }
}

// ---------------------------------------------------------------------------
// loss = sum_r L1^2 + L2^2 + L3^2 + (0.5*(L4row + who_b) - Y)^2
__global__ __launch_bounds__(1024) void final_reduce(
    const float* __restrict__ L1, const float* __restrict__ L2,
    const float* __restrict__ L3, const float* __restrict__ L4,
    const float* __restrict__ Y, const float* __restrict__ whob,
    float* __restrict__ out) {
    float s = 0.f;
    float wb = whob[0];
    for (int r = threadIdx.x; r < NR; r += 1024) {
        float l4 = 0.5f * (L4[r] + wb) - Y[r];
        s += L1[r] * L1[r] + L2[r] * L2[r] + L3[r] * L3[r] + l4 * l4;
    }
#pragma unroll
    for (int off = 1; off < 64; off <<= 1) s += __shfl_xor(s, off, 64);
    __shared__ float sm[16];
    int w = threadIdx.x >> 6, ln = threadIdx.x & 63;
    if (ln == 0) sm[w] = s;
    __syncthreads();
    if (threadIdx.x == 0) {
        float t = 0.f;
#pragma unroll
        for (int i = 0; i < 16; ++i) t += sm[i];
        out[0] = t;
    }
}

// ---------------------------------------------------------------------------
extern "C" void kernel_launch(void* const* d_in, const int* in_sizes, int n_in,
                              void* d_out, int out_size, void* d_ws, size_t ws_size,
                              hipStream_t stream) {
    const float* X1   = (const float*)d_in[0];
    const float* X2   = (const float*)d_in[1];
    const float* Y    = (const float*)d_in[2];
    const float* w1hW = (const float*)d_in[3];
    const float* w1hb = (const float*)d_in[4];
    const float* w2hW = (const float*)d_in[5];
    const float* w2hb = (const float*)d_in[6];
    const float* wh1W = (const float*)d_in[7];
    const float* wh1b = (const float*)d_in[8];
    const float* wh2W = (const float*)d_in[9];
    const float* wh2b = (const float*)d_in[10];
    const float* whoW = (const float*)d_in[11];
    const float* whob = (const float*)d_in[12];

    // workspace layout (~208.3 MB total)
    char* ws = (char*)d_ws;
    u16* X1h  = (u16*)(ws);                               // 16384x1024 fp16
    u16* X2h  = X1h + (size_t)NR * DX;
    u16* H1h  = X2h + (size_t)NR * DX;                    // 16384x2048 fp16
    u16* H2h  = H1h + (size_t)NR * DH;
    u16* w1hT = H2h + (size_t)NR * DH;                    // [DH][DX]
    u16* w2hT = w1hT + (size_t)DH * DX;
    u16* wh1T = w2hT + (size_t)DH * DX;                   // [DX][DH]
    u16* wh2T = wh1T + (size_t)DX * DH;
    float* L1a = (float*)(wh2T + (size_t)DX * DH);        // 4 x 16384 f32
    float* L2a = L1a + NR;
    float* L3a = L2a + NR;
    float* L4a = L3a + NR;

    // zero the atomically-accumulated arrays (ws is poisoned 0xAA each call)
    hipMemsetAsync(L1a, 0, 2 * (size_t)NR * sizeof(float), stream);

    // casts
    cast_f32_f16<<<NR * DX / 1024, 256, 0, stream>>>(X1, X1h);
    cast_f32_f16<<<NR * DX / 1024, 256, 0, stream>>>(X2, X2h);
    transpose_cast<<<dim3(DH / 32, DX / 32), 256, 0, stream>>>(w1hW, w1hT, DX, DH);
    transpose_cast<<<dim3(DH / 32, DX / 32), 256, 0, stream>>>(w2hW, w2hT, DX, DH);
    transpose_cast<<<dim3(DX / 32, DH / 32), 256, 0, stream>>>(wh1W, wh1T, DH, DX);
    transpose_cast<<<dim3(DX / 32, DH / 32), 256, 0, stream>>>(wh2W, wh2T, DH, DX);

    // H1 = X1@w1h + b, H2 = X2@w2h + b  (fp16 out)
    // grid.x = N-tiles (consecutive blocks share the A slab -> L2 reuse)
    gemm_bt<0><<<dim3(DH / 128, NR / 128), 256, 0, stream>>>(
        X1h, w1hT, w1hb, H1h, nullptr, nullptr, NR, DH, DX);
    gemm_bt<0><<<dim3(DH / 128, NR / 128), 256, 0, stream>>>(
        X2h, w2hT, w2hb, H2h, nullptr, nullptr, NR, DH, DX);

    // L3, L4row from H1, H2
    l34_kernel<<<NR, 256, 0, stream>>>(H1h, H2h, whoW, L3a, L4a);

    // L1 = rowsq(H1@wh2 + b - X2), L2 = rowsq(H2@wh1 + b - X1)
    gemm_bt<1><<<dim3(DX / 128, NR / 128), 256, 0, stream>>>(
        H1h, wh2T, wh2b, nullptr, X2, L1a, NR, DX, DH);
    gemm_bt<1><<<dim3(DX / 128, NR / 128), 256, 0, stream>>>(
        H2h, wh1T, wh1b, nullptr, X1, L2a, NR, DX, DH);

    final_reduce<<<1, 1024, 0, stream>>>(L1a, L2a, L3a, L4a, Y, whob, (float*)d_out);
}

// Round 3
// 803.121 us; speedup vs baseline: 1.0535x; 1.0535x over previous
//
#include <hip/hip_runtime.h>
#include <cstdint>
#include <cstddef>

// Problem constants (reference: N=16384, DX1=DX2=1024, DH=2048)
#define NR 16384
#define DX 1024
#define DH 2048

typedef unsigned short u16;
typedef _Float16 half8 __attribute__((ext_vector_type(8)));
typedef _Float16 half4v __attribute__((ext_vector_type(4)));
typedef float f32x16 __attribute__((ext_vector_type(16)));

__device__ __forceinline__ u16 f2h_bits(float v) {
    union { _Float16 h; u16 u; } c;
    c.h = (_Float16)v;
    return c.u;
}

// async global->LDS, 16B per lane; LDS dest = wave-uniform base + lane*16
__device__ __forceinline__ void gl_lds16(const void* g, void* l) {
    __builtin_amdgcn_global_load_lds(
        (const __attribute__((address_space(1))) void*)g,
        (__attribute__((address_space(3))) void*)l, 16, 0, 0);
}

// ---------------------------------------------------------------------------
// fp32 -> fp16 elementwise cast (vectorized float4 -> half4). n must be %1024.
__global__ __launch_bounds__(256) void cast_f32_f16(const float* __restrict__ in,
                                                    u16* __restrict__ out) {
    size_t i = ((size_t)blockIdx.x * 256 + threadIdx.x) * 4;
    float4 v = *(const float4*)&in[i];
    half4v o = { (_Float16)v.x, (_Float16)v.y, (_Float16)v.z, (_Float16)v.w };
    *(half4v*)&out[i] = o;
}

// ---------------------------------------------------------------------------
// W [K,D] fp32 -> Wt [D,K] fp16 (LDS tiled transpose). K,D % 32 == 0.
__global__ __launch_bounds__(256) void transpose_cast(const float* __restrict__ in,
                                                      u16* __restrict__ out,
                                                      int K, int D) {
    __shared__ float tile[32][33];
    int tx = threadIdx.x & 31;
    int ty = threadIdx.x >> 5;                  // 0..7
    int d0 = blockIdx.x * 32, k0 = blockIdx.y * 32;
#pragma unroll
    for (int i = 0; i < 32; i += 8)
        tile[ty + i][tx] = in[(size_t)(k0 + ty + i) * D + d0 + tx];
    __syncthreads();
#pragma unroll
    for (int i = 0; i < 32; i += 8)
        out[(size_t)(d0 + ty + i) * K + k0 + tx] = f2h_bits(tile[tx][ty + i]);
}

// ---------------------------------------------------------------------------
// 128x128-tile GEMM, BK=64, 256 threads (4 waves 2x2), 32x32x16 f16 MFMA.
// A [M,K] fp16 row-major, Bt [N,K] fp16 row-major (i.e. B transposed).
//
// LDS "chunk" layout (verified r2): chunk (rt, ks) holds, at lane L's slot
// (chunk*1024B + L*16B), the 8 halfs A[rt*32 + (L&31)][ks*16 + (L>>5)*8 ..+8]
// == the 32x32x16 MFMA fragment pattern -> all ds_read_b128 conflict-free.
//
// XCD-banded 1D grid: xcd = blockIdx.x & 7 owns M-band [xcd*16 .. xcd*16+15]
// tiles (A fetched once per XCD band). Within a band: panels of P m-tiles
// (panel A ~2MB resident in the XCD's 4MB L2), n middle, m-in-panel inner,
// so each B-slab is touched by P temporally-adjacent blocks.
//
// Double-buffered 1-barrier pipeline: prefetch slab k+1 after the barrier,
// compute slab k; the barrier's vmcnt(0) drain targets loads issued one full
// MFMA phase ago -> near-zero drain stall. LDS 64 KB -> 2 blocks/CU.
//
// MODE 0: C[M,N] = A@B + bias   (fp16 out)
// MODE 1: Lacc[row] += sum_col (A@B + bias - Xref)^2   (atomic per row)
template <int MODE>
__global__ __launch_bounds__(256) void gemm_bt(
    const u16* __restrict__ A, const u16* __restrict__ Bt,
    const float* __restrict__ bias,
    u16* __restrict__ C, const _Float16* __restrict__ Xref,
    float* __restrict__ Lacc,
    int M, int N, int K, int NT, int P) {
    __shared__ __align__(16) u16 As[2][128 * 64];   // 2 x 16 KB
    __shared__ __align__(16) u16 Bs[2][128 * 64];   // 2 x 16 KB

    const int tid  = threadIdx.x;
    const int lane = tid & 63;
    const int w    = tid >> 6;
    const int wr   = w >> 1, wc = w & 1;
    const int l31 = lane & 31, h = lane >> 5;

    // ---- XCD-banded tile decode ----
    const int b    = blockIdx.x;
    const int xcd  = b & 7;
    const int slot = b >> 3;
    const int perPanel = NT * P;
    const int p    = slot / perPanel;
    const int rem  = slot - p * perPanel;
    const int n_t  = rem / P;
    const int mi   = rem - n_t * P;
    const int mPerX = (M >> 7) >> 3;               // (M/128)/8
    const int m0 = (xcd * mPerX + p * P + mi) * 128;
    const int n0 = n_t * 128;

    f32x16 acc[2][2] = {};

    // staging: 32 chunks of 1KB per BK=64 slab; wave w stages chunks w*8..w*8+7
    const u16* gsrc[8];
    int loff[8];        // chunk offset within As[buf]/Bs[buf] (halfs)
    bool isA[8];
#pragma unroll
    for (int cc = 0; cc < 8; ++cc) {
        int c = w * 8 + cc;                        // wave-uniform
        int rt = (c >> 2) & 3, ks = c & 3;
        int row = rt * 32 + l31;
        int ko  = ks * 16 + h * 8;
        isA[cc] = (c < 16);
        if (c < 16) gsrc[cc] = A  + (size_t)(m0 + row) * K + ko;
        else        gsrc[cc] = Bt + (size_t)(n0 + row) * K + ko;
        loff[cc] = (rt * 4 + ks) * 512;
    }

    const int nIter = K >> 6;
    // prefetch slab 0 into buffer 0
#pragma unroll
    for (int cc = 0; cc < 8; ++cc)
        gl_lds16(gsrc[cc], (isA[cc] ? &As[0][loff[cc]] : &Bs[0][loff[cc]]));

    for (int it = 0; it < nIter; ++it) {
        __syncthreads();   // drains the loads for buffer (it&1), issued 1 iter ago
        if (it + 1 < nIter) {
            int nb = (it + 1) & 1;
            int kt = (it + 1) << 6;
#pragma unroll
            for (int cc = 0; cc < 8; ++cc)
                gl_lds16(gsrc[cc] + kt,
                         (isA[cc] ? &As[nb][loff[cc]] : &Bs[nb][loff[cc]]));
        }
        const int cur = it & 1;
#pragma unroll
        for (int ks = 0; ks < 4; ++ks) {
            half8 af[2], bf[2];
#pragma unroll
            for (int i = 0; i < 2; ++i) {
                af[i] = *(const half8*)&As[cur][((wr * 2 + i) * 4 + ks) * 512 + lane * 8];
                bf[i] = *(const half8*)&Bs[cur][((wc * 2 + i) * 4 + ks) * 512 + lane * 8];
            }
#pragma unroll
            for (int i = 0; i < 2; ++i)
#pragma unroll
                for (int j = 0; j < 2; ++j)
                    acc[i][j] = __builtin_amdgcn_mfma_f32_32x32x16_f16(
                        af[i], bf[j], acc[i][j], 0, 0, 0);
        }
    }

    // epilogue: 32x32 C/D layout col = lane&31, row = (r&3) + 8*(r>>2) + 4*h
    const int colb = n0 + wc * 64 + l31;
    float bj0 = bias[colb], bj1 = bias[colb + 32];

    if (MODE == 0) {
#pragma unroll
        for (int i = 0; i < 2; ++i) {
            int rowb = m0 + wr * 64 + i * 32 + 4 * h;
#pragma unroll
            for (int r = 0; r < 16; ++r) {
                int row = rowb + (r & 3) + 8 * (r >> 2);
                size_t ro = (size_t)row * N + colb;
                C[ro]      = f2h_bits(acc[i][0][r] + bj0);
                C[ro + 32] = f2h_bits(acc[i][1][r] + bj1);
            }
        }
    } else {
#pragma unroll
        for (int i = 0; i < 2; ++i) {
            int rowb = m0 + wr * 64 + i * 32 + 4 * h;
#pragma unroll
            for (int r = 0; r < 16; ++r) {
                int row = rowb + (r & 3) + 8 * (r >> 2);
                size_t ro = (size_t)row * N + colb;
                float d0 = acc[i][0][r] + bj0 - (float)Xref[ro];
                float d1 = acc[i][1][r] + bj1 - (float)Xref[ro + 32];
                float s = d0 * d0 + d1 * d1;
                // reduce over the 32 lanes (cols) sharing this row
                s += __shfl_xor(s, 1, 64);
                s += __shfl_xor(s, 2, 64);
                s += __shfl_xor(s, 4, 64);
                s += __shfl_xor(s, 8, 64);
                s += __shfl_xor(s, 16, 64);
                if (l31 == 0) atomicAdd(&Lacc[row], s);
            }
        }
    }
}

// ---------------------------------------------------------------------------
// Per-row L3 = sum (h1-h2)^2 and L4row = sum (h1+h2)*whoW. One block per row.
__global__ __launch_bounds__(256) void l34_kernel(
    const u16* __restrict__ H1, const u16* __restrict__ H2,
    const float* __restrict__ whoW,
    float* __restrict__ L3, float* __restrict__ L4) {
    int row = blockIdx.x;
    int tid = threadIdx.x;
    const half8 h1 = *(const half8*)&H1[(size_t)row * DH + tid * 8];
    const half8 h2 = *(const half8*)&H2[(size_t)row * DH + tid * 8];
    float4 w0 = *(const float4*)&whoW[tid * 8];
    float4 w1 = *(const float4*)&whoW[tid * 8 + 4];
    float wv[8] = { w0.x, w0.y, w0.z, w0.w, w1.x, w1.y, w1.z, w1.w };
    float s3 = 0.f, s4 = 0.f;
#pragma unroll
    for (int u = 0; u < 8; ++u) {
        float a = (float)h1[u], b = (float)h2[u];
        float d = a - b;
        s3 += d * d;
        s4 += (a + b) * wv[u];
    }
#pragma unroll
    for (int off = 1; off < 64; off <<= 1) {
        s3 += __shfl_xor(s3, off, 64);
        s4 += __shfl_xor(s4, off, 64);
    }
    __shared__ float sm[8];
    int wvi = tid >> 6, ln = tid & 63;
    if (ln == 0) { sm[wvi] = s3; sm[4 + wvi] = s4; }
    __syncthreads();
    if (tid == 0) {
        L3[row] = sm[0] + sm[1] + sm[2] + sm[3];
        L4[row] = sm[4] + sm[5] + sm[6] + sm[7];
    }
}

// ---------------------------------------------------------------------------
// loss = sum_r L1^2 + L2^2 + L3^2 + (0.5*(L4row + who_b) - Y)^2
__global__ __launch_bounds__(1024) void final_reduce(
    const float* __restrict__ L1, const float* __restrict__ L2,
    const float* __restrict__ L3, const float* __restrict__ L4,
    const float* __restrict__ Y, const float* __restrict__ whob,
    float* __restrict__ out) {
    float s = 0.f;
    float wb = whob[0];
    for (int r = threadIdx.x; r < NR; r += 1024) {
        float l4 = 0.5f * (L4[r] + wb) - Y[r];
        s += L1[r] * L1[r] + L2[r] * L2[r] + L3[r] * L3[r] + l4 * l4;
    }
#pragma unroll
    for (int off = 1; off < 64; off <<= 1) s += __shfl_xor(s, off, 64);
    __shared__ float sm[16];
    int w = threadIdx.x >> 6, ln = threadIdx.x & 63;
    if (ln == 0) sm[w] = s;
    __syncthreads();
    if (threadIdx.x == 0) {
        float t = 0.f;
#pragma unroll
        for (int i = 0; i < 16; ++i) t += sm[i];
        out[0] = t;
    }
}

// ---------------------------------------------------------------------------
extern "C" void kernel_launch(void* const* d_in, const int* in_sizes, int n_in,
                              void* d_out, int out_size, void* d_ws, size_t ws_size,
                              hipStream_t stream) {
    const float* X1   = (const float*)d_in[0];
    const float* X2   = (const float*)d_in[1];
    const float* Y    = (const float*)d_in[2];
    const float* w1hW = (const float*)d_in[3];
    const float* w1hb = (const float*)d_in[4];
    const float* w2hW = (const float*)d_in[5];
    const float* w2hb = (const float*)d_in[6];
    const float* wh1W = (const float*)d_in[7];
    const float* wh1b = (const float*)d_in[8];
    const float* wh2W = (const float*)d_in[9];
    const float* wh2b = (const float*)d_in[10];
    const float* whoW = (const float*)d_in[11];
    const float* whob = (const float*)d_in[12];

    // workspace layout (~208.3 MB total)
    char* ws = (char*)d_ws;
    u16* X1h  = (u16*)(ws);                               // 16384x1024 fp16
    u16* X2h  = X1h + (size_t)NR * DX;
    u16* H1h  = X2h + (size_t)NR * DX;                    // 16384x2048 fp16
    u16* H2h  = H1h + (size_t)NR * DH;
    u16* w1hT = H2h + (size_t)NR * DH;                    // [DH][DX]
    u16* w2hT = w1hT + (size_t)DH * DX;
    u16* wh1T = w2hT + (size_t)DH * DX;                   // [DX][DH]
    u16* wh2T = wh1T + (size_t)DX * DH;
    float* L1a = (float*)(wh2T + (size_t)DX * DH);        // 4 x 16384 f32
    float* L2a = L1a + NR;
    float* L3a = L2a + NR;
    float* L4a = L3a + NR;

    // zero the atomically-accumulated arrays (ws is poisoned 0xAA each call)
    hipMemsetAsync(L1a, 0, 2 * (size_t)NR * sizeof(float), stream);

    // casts
    cast_f32_f16<<<NR * DX / 1024, 256, 0, stream>>>(X1, X1h);
    cast_f32_f16<<<NR * DX / 1024, 256, 0, stream>>>(X2, X2h);
    transpose_cast<<<dim3(DH / 32, DX / 32), 256, 0, stream>>>(w1hW, w1hT, DX, DH);
    transpose_cast<<<dim3(DH / 32, DX / 32), 256, 0, stream>>>(w2hW, w2hT, DX, DH);
    transpose_cast<<<dim3(DX / 32, DH / 32), 256, 0, stream>>>(wh1W, wh1T, DH, DX);
    transpose_cast<<<dim3(DX / 32, DH / 32), 256, 0, stream>>>(wh2W, wh2T, DH, DX);

    // H1 = X1@w1h + b, H2 = X2@w2h + b  (fp16 out). K=1024 -> panel P=8.
    gemm_bt<0><<<(NR / 128) * (DH / 128), 256, 0, stream>>>(
        X1h, w1hT, w1hb, H1h, nullptr, nullptr, NR, DH, DX, DH / 128, 8);
    gemm_bt<0><<<(NR / 128) * (DH / 128), 256, 0, stream>>>(
        X2h, w2hT, w2hb, H2h, nullptr, nullptr, NR, DH, DX, DH / 128, 8);

    // L3, L4row from H1, H2
    l34_kernel<<<NR, 256, 0, stream>>>(H1h, H2h, whoW, L3a, L4a);

    // L1 = rowsq(H1@wh2 + b - X2), L2 = rowsq(H2@wh1 + b - X1). K=2048 -> P=4.
    gemm_bt<1><<<(NR / 128) * (DX / 128), 256, 0, stream>>>(
        H1h, wh2T, wh2b, nullptr, (const _Float16*)X2h, L1a, NR, DX, DH, DX / 128, 4);
    gemm_bt<1><<<(NR / 128) * (DX / 128), 256, 0, stream>>>(
        H2h, wh1T, wh1b, nullptr, (const _Float16*)X1h, L2a, NR, DX, DH, DX / 128, 4);

    final_reduce<<<1, 1024, 0, stream>>>(L1a, L2a, L3a, L4a, Y, whob, (float*)d_out);
}

// Round 4
// 791.758 us; speedup vs baseline: 1.0686x; 1.0144x over previous
//
#include <hip/hip_runtime.h>
#include <cstdint>
#include <cstddef>

// Problem constants (reference: N=16384, DX1=DX2=1024, DH=2048)
#define NR 16384
#define DX 1024
#define DH 2048

typedef unsigned short u16;
typedef _Float16 half8 __attribute__((ext_vector_type(8)));
typedef _Float16 half4v __attribute__((ext_vector_type(4)));
typedef float f32x16 __attribute__((ext_vector_type(16)));

__device__ __forceinline__ u16 f2h_bits(float v) {
    union { _Float16 h; u16 u; } c;
    c.h = (_Float16)v;
    return c.u;
}

// async global->LDS, 16B per lane; LDS dest = wave-uniform base + lane*16
__device__ __forceinline__ void gl_lds16(const void* g, void* l) {
    __builtin_amdgcn_global_load_lds(
        (const __attribute__((address_space(1))) void*)g,
        (__attribute__((address_space(3))) void*)l, 16, 0, 0);
}

// ---------------------------------------------------------------------------
// fp32 -> fp16 elementwise cast (vectorized float4 -> half4). n must be %1024.
__global__ __launch_bounds__(256) void cast_f32_f16(const float* __restrict__ in,
                                                    u16* __restrict__ out) {
    size_t i = ((size_t)blockIdx.x * 256 + threadIdx.x) * 4;
    float4 v = *(const float4*)&in[i];
    half4v o = { (_Float16)v.x, (_Float16)v.y, (_Float16)v.z, (_Float16)v.w };
    *(half4v*)&out[i] = o;
}

// ---------------------------------------------------------------------------
// W [K,D] fp32 -> Wt [D,K] fp16 (LDS tiled transpose). K,D % 32 == 0.
__global__ __launch_bounds__(256) void transpose_cast(const float* __restrict__ in,
                                                      u16* __restrict__ out,
                                                      int K, int D) {
    __shared__ float tile[32][33];
    int tx = threadIdx.x & 31;
    int ty = threadIdx.x >> 5;                  // 0..7
    int d0 = blockIdx.x * 32, k0 = blockIdx.y * 32;
#pragma unroll
    for (int i = 0; i < 32; i += 8)
        tile[ty + i][tx] = in[(size_t)(k0 + ty + i) * D + d0 + tx];
    __syncthreads();
#pragma unroll
    for (int i = 0; i < 32; i += 8)
        out[(size_t)(d0 + ty + i) * K + k0 + tx] = f2h_bits(tile[tx][ty + i]);
}

// ---------------------------------------------------------------------------
// 128x128-tile GEMM, BK=32, 256 threads (4 waves 2x2), 32x32x16 f16 MFMA.
// A [M,K] fp16 row-major, Bt [N,K] fp16 row-major (i.e. B transposed).
//
// LDS "chunk" layout (verified r2): chunk (rt, ks) holds, at lane L's slot
// (chunk*1024B + L*16B), the 8 halfs A[rt*32 + (L&31)][ks*16 + (L>>5)*8 ..+8]
// == the 32x32x16 MFMA fragment pattern -> all ds_read_b128 conflict-free
// (verified r2/r3: SQ_LDS_BANK_CONFLICT = 0).
//
// XCD-banded 1D grid (verified r3: FETCH at compulsory minimum): xcd = b & 7
// owns M-band; panels of P m-tiles (~2MB A in the XCD's L2), n middle.
//
// Double-buffered 1-barrier pipeline with BK=32: LDS = 2*16 KB = 32 KB ->
// 5 blocks/CU (r3's BK=64 gave 64 KB -> 2 blocks/CU -> latency-bound,
// MfmaUtil 16.7%). 20 waves/CU hide the per-slab load latency.
//
// MODE 0: C[M,N] = A@B + bias   (fp16 out)
// MODE 1: Lacc[row] += sum_col (A@B + bias - Xref)^2   (atomic per row)
template <int MODE>
__global__ __launch_bounds__(256) void gemm_bt(
    const u16* __restrict__ A, const u16* __restrict__ Bt,
    const float* __restrict__ bias,
    u16* __restrict__ C, const _Float16* __restrict__ Xref,
    float* __restrict__ Lacc,
    int M, int N, int K, int NT, int P) {
    __shared__ __align__(16) u16 As[2][128 * 32];   // 2 x 8 KB
    __shared__ __align__(16) u16 Bs[2][128 * 32];   // 2 x 8 KB

    const int tid  = threadIdx.x;
    const int lane = tid & 63;
    const int w    = tid >> 6;
    const int wr   = w >> 1, wc = w & 1;
    const int l31 = lane & 31, h = lane >> 5;

    // ---- XCD-banded tile decode ----
    const int b    = blockIdx.x;
    const int xcd  = b & 7;
    const int slot = b >> 3;
    const int perPanel = NT * P;
    const int p    = slot / perPanel;
    const int rem  = slot - p * perPanel;
    const int n_t  = rem / P;
    const int mi   = rem - n_t * P;
    const int mPerX = (M >> 7) >> 3;               // (M/128)/8
    const int m0 = (xcd * mPerX + p * P + mi) * 128;
    const int n0 = n_t * 128;

    f32x16 acc[2][2] = {};

    // staging: 16 chunks of 1KB per BK=32 slab; wave w stages chunks w*4..w*4+3
    const u16* gsrc[4];
    int loff[4];        // chunk offset within As[buf]/Bs[buf] (halfs)
    bool isA[4];
#pragma unroll
    for (int cc = 0; cc < 4; ++cc) {
        int c = w * 4 + cc;                        // wave-uniform
        int ci = c & 7;
        int rt = ci >> 1, ks = ci & 1;
        int row = rt * 32 + l31;
        int ko  = ks * 16 + h * 8;
        isA[cc] = (c < 8);
        if (c < 8) gsrc[cc] = A  + (size_t)(m0 + row) * K + ko;
        else       gsrc[cc] = Bt + (size_t)(n0 + row) * K + ko;
        loff[cc] = (rt * 2 + ks) * 512;
    }

    const int nIter = K >> 5;
    // prefetch slab 0 into buffer 0
#pragma unroll
    for (int cc = 0; cc < 4; ++cc)
        gl_lds16(gsrc[cc], (isA[cc] ? &As[0][loff[cc]] : &Bs[0][loff[cc]]));

    for (int it = 0; it < nIter; ++it) {
        __syncthreads();   // drains the loads for buffer (it&1), issued 1 iter ago
        if (it + 1 < nIter) {
            int nb = (it + 1) & 1;
            int kt = (it + 1) << 5;
#pragma unroll
            for (int cc = 0; cc < 4; ++cc)
                gl_lds16(gsrc[cc] + kt,
                         (isA[cc] ? &As[nb][loff[cc]] : &Bs[nb][loff[cc]]));
        }
        const int cur = it & 1;
#pragma unroll
        for (int ks = 0; ks < 2; ++ks) {
            half8 af[2], bf[2];
#pragma unroll
            for (int i = 0; i < 2; ++i) {
                af[i] = *(const half8*)&As[cur][((wr * 2 + i) * 2 + ks) * 512 + lane * 8];
                bf[i] = *(const half8*)&Bs[cur][((wc * 2 + i) * 2 + ks) * 512 + lane * 8];
            }
#pragma unroll
            for (int i = 0; i < 2; ++i)
#pragma unroll
                for (int j = 0; j < 2; ++j)
                    acc[i][j] = __builtin_amdgcn_mfma_f32_32x32x16_f16(
                        af[i], bf[j], acc[i][j], 0, 0, 0);
        }
    }

    // epilogue: 32x32 C/D layout col = lane&31, row = (r&3) + 8*(r>>2) + 4*h
    const int colb = n0 + wc * 64 + l31;
    float bj0 = bias[colb], bj1 = bias[colb + 32];

    if (MODE == 0) {
#pragma unroll
        for (int i = 0; i < 2; ++i) {
            int rowb = m0 + wr * 64 + i * 32 + 4 * h;
#pragma unroll
            for (int r = 0; r < 16; ++r) {
                int row = rowb + (r & 3) + 8 * (r >> 2);
                size_t ro = (size_t)row * N + colb;
                C[ro]      = f2h_bits(acc[i][0][r] + bj0);
                C[ro + 32] = f2h_bits(acc[i][1][r] + bj1);
            }
        }
    } else {
#pragma unroll
        for (int i = 0; i < 2; ++i) {
            int rowb = m0 + wr * 64 + i * 32 + 4 * h;
#pragma unroll
            for (int r = 0; r < 16; ++r) {
                int row = rowb + (r & 3) + 8 * (r >> 2);
                size_t ro = (size_t)row * N + colb;
                float d0 = acc[i][0][r] + bj0 - (float)Xref[ro];
                float d1 = acc[i][1][r] + bj1 - (float)Xref[ro + 32];
                float s = d0 * d0 + d1 * d1;
                // reduce over the 32 lanes (cols) sharing this row
                s += __shfl_xor(s, 1, 64);
                s += __shfl_xor(s, 2, 64);
                s += __shfl_xor(s, 4, 64);
                s += __shfl_xor(s, 8, 64);
                s += __shfl_xor(s, 16, 64);
                if (l31 == 0) atomicAdd(&Lacc[row], s);
            }
        }
    }
}

// ---------------------------------------------------------------------------
// Per-row L3 = sum (h1-h2)^2 and L4row = sum (h1+h2)*whoW. One block per row.
__global__ __launch_bounds__(256) void l34_kernel(
    const u16* __restrict__ H1, const u16* __restrict__ H2,
    const float* __restrict__ whoW,
    float* __restrict__ L3, float* __restrict__ L4) {
    int row = blockIdx.x;
    int tid = threadIdx.x;
    const half8 h1 = *(const half8*)&H1[(size_t)row * DH + tid * 8];
    const half8 h2 = *(const half8*)&H2[(size_t)row * DH + tid * 8];
    float4 w0 = *(const float4*)&whoW[tid * 8];
    float4 w1 = *(const float4*)&whoW[tid * 8 + 4];
    float wv[8] = { w0.x, w0.y, w0.z, w0.w, w1.x, w1.y, w1.z, w1.w };
    float s3 = 0.f, s4 = 0.f;
#pragma unroll
    for (int u = 0; u < 8; ++u) {
        float a = (float)h1[u], b = (float)h2[u];
        float d = a - b;
        s3 += d * d;
        s4 += (a + b) * wv[u];
    }
#pragma unroll
    for (int off = 1; off < 64; off <<= 1) {
        s3 += __shfl_xor(s3, off, 64);
        s4 += __shfl_xor(s4, off, 64);
    }
    __shared__ float sm[8];
    int wvi = tid >> 6, ln = tid & 63;
    if (ln == 0) { sm[wvi] = s3; sm[4 + wvi] = s4; }
    __syncthreads();
    if (tid == 0) {
        L3[row] = sm[0] + sm[1] + sm[2] + sm[3];
        L4[row] = sm[4] + sm[5] + sm[6] + sm[7];
    }
}

// ---------------------------------------------------------------------------
// loss = sum_r L1^2 + L2^2 + L3^2 + (0.5*(L4row + who_b) - Y)^2
__global__ __launch_bounds__(1024) void final_reduce(
    const float* __restrict__ L1, const float* __restrict__ L2,
    const float* __restrict__ L3, const float* __restrict__ L4,
    const float* __restrict__ Y, const float* __restrict__ whob,
    float* __restrict__ out) {
    float s = 0.f;
    float wb = whob[0];
    for (int r = threadIdx.x; r < NR; r += 1024) {
        float l4 = 0.5f * (L4[r] + wb) - Y[r];
        s += L1[r] * L1[r] + L2[r] * L2[r] + L3[r] * L3[r] + l4 * l4;
    }
#pragma unroll
    for (int off = 1; off < 64; off <<= 1) s += __shfl_xor(s, off, 64);
    __shared__ float sm[16];
    int w = threadIdx.x >> 6, ln = threadIdx.x & 63;
    if (ln == 0) sm[w] = s;
    __syncthreads();
    if (threadIdx.x == 0) {
        float t = 0.f;
#pragma unroll
        for (int i = 0; i < 16; ++i) t += sm[i];
        out[0] = t;
    }
}

// ---------------------------------------------------------------------------
extern "C" void kernel_launch(void* const* d_in, const int* in_sizes, int n_in,
                              void* d_out, int out_size, void* d_ws, size_t ws_size,
                              hipStream_t stream) {
    const float* X1   = (const float*)d_in[0];
    const float* X2   = (const float*)d_in[1];
    const float* Y    = (const float*)d_in[2];
    const float* w1hW = (const float*)d_in[3];
    const float* w1hb = (const float*)d_in[4];
    const float* w2hW = (const float*)d_in[5];
    const float* w2hb = (const float*)d_in[6];
    const float* wh1W = (const float*)d_in[7];
    const float* wh1b = (const float*)d_in[8];
    const float* wh2W = (const float*)d_in[9];
    const float* wh2b = (const float*)d_in[10];
    const float* whoW = (const float*)d_in[11];
    const float* whob = (const float*)d_in[12];

    // workspace layout (~208.3 MB total)
    char* ws = (char*)d_ws;
    u16* X1h  = (u16*)(ws);                               // 16384x1024 fp16
    u16* X2h  = X1h + (size_t)NR * DX;
    u16* H1h  = X2h + (size_t)NR * DX;                    // 16384x2048 fp16
    u16* H2h  = H1h + (size_t)NR * DH;
    u16* w1hT = H2h + (size_t)NR * DH;                    // [DH][DX]
    u16* w2hT = w1hT + (size_t)DH * DX;
    u16* wh1T = w2hT + (size_t)DH * DX;                   // [DX][DH]
    u16* wh2T = wh1T + (size_t)DX * DH;
    float* L1a = (float*)(wh2T + (size_t)DX * DH);        // 4 x 16384 f32
    float* L2a = L1a + NR;
    float* L3a = L2a + NR;
    float* L4a = L3a + NR;

    // zero the atomically-accumulated arrays (ws is poisoned 0xAA each call)
    hipMemsetAsync(L1a, 0, 2 * (size_t)NR * sizeof(float), stream);

    // casts
    cast_f32_f16<<<NR * DX / 1024, 256, 0, stream>>>(X1, X1h);
    cast_f32_f16<<<NR * DX / 1024, 256, 0, stream>>>(X2, X2h);
    transpose_cast<<<dim3(DH / 32, DX / 32), 256, 0, stream>>>(w1hW, w1hT, DX, DH);
    transpose_cast<<<dim3(DH / 32, DX / 32), 256, 0, stream>>>(w2hW, w2hT, DX, DH);
    transpose_cast<<<dim3(DX / 32, DH / 32), 256, 0, stream>>>(wh1W, wh1T, DH, DX);
    transpose_cast<<<dim3(DX / 32, DH / 32), 256, 0, stream>>>(wh2W, wh2T, DH, DX);

    // H1 = X1@w1h + b, H2 = X2@w2h + b  (fp16 out). K=1024 -> panel P=8.
    gemm_bt<0><<<(NR / 128) * (DH / 128), 256, 0, stream>>>(
        X1h, w1hT, w1hb, H1h, nullptr, nullptr, NR, DH, DX, DH / 128, 8);
    gemm_bt<0><<<(NR / 128) * (DH / 128), 256, 0, stream>>>(
        X2h, w2hT, w2hb, H2h, nullptr, nullptr, NR, DH, DX, DH / 128, 8);

    // L3, L4row from H1, H2
    l34_kernel<<<NR, 256, 0, stream>>>(H1h, H2h, whoW, L3a, L4a);

    // L1 = rowsq(H1@wh2 + b - X2), L2 = rowsq(H2@wh1 + b - X1). K=2048 -> P=4.
    gemm_bt<1><<<(NR / 128) * (DX / 128), 256, 0, stream>>>(
        H1h, wh2T, wh2b, nullptr, (const _Float16*)X2h, L1a, NR, DX, DH, DX / 128, 4);
    gemm_bt<1><<<(NR / 128) * (DX / 128), 256, 0, stream>>>(
        H2h, wh1T, wh1b, nullptr, (const _Float16*)X1h, L2a, NR, DX, DH, DX / 128, 4);

    final_reduce<<<1, 1024, 0, stream>>>(L1a, L2a, L3a, L4a, Y, whob, (float*)d_out);
}

// Round 5
// 765.715 us; speedup vs baseline: 1.1050x; 1.0340x over previous
//
#include <hip/hip_runtime.h>
#include <cstdint>
#include <cstddef>

// Problem constants (reference: N=16384, DX1=DX2=1024, DH=2048)
#define NR 16384
#define DX 1024
#define DH 2048

typedef unsigned short u16;
typedef _Float16 half8 __attribute__((ext_vector_type(8)));
typedef _Float16 half4v __attribute__((ext_vector_type(4)));
typedef float f32x16 __attribute__((ext_vector_type(16)));

__device__ __forceinline__ u16 f2h_bits(float v) {
    union { _Float16 h; u16 u; } c;
    c.h = (_Float16)v;
    return c.u;
}

// async global->LDS, 16B per lane; LDS dest = wave-uniform base + lane*16
__device__ __forceinline__ void gl_lds16(const void* g, void* l) {
    __builtin_amdgcn_global_load_lds(
        (const __attribute__((address_space(1))) void*)g,
        (__attribute__((address_space(3))) void*)l, 16, 0, 0);
}

// ---------------------------------------------------------------------------
// fp32 -> fp16 elementwise cast (vectorized float4 -> half4). n must be %1024.
__global__ __launch_bounds__(256) void cast_f32_f16(const float* __restrict__ in,
                                                    u16* __restrict__ out) {
    size_t i = ((size_t)blockIdx.x * 256 + threadIdx.x) * 4;
    float4 v = *(const float4*)&in[i];
    half4v o = { (_Float16)v.x, (_Float16)v.y, (_Float16)v.z, (_Float16)v.w };
    *(half4v*)&out[i] = o;
}

// ---------------------------------------------------------------------------
// W [K,D] fp32 -> Wt [D,K] fp16 (LDS tiled transpose). K,D % 32 == 0.
__global__ __launch_bounds__(256) void transpose_cast(const float* __restrict__ in,
                                                      u16* __restrict__ out,
                                                      int K, int D) {
    __shared__ float tile[32][33];
    int tx = threadIdx.x & 31;
    int ty = threadIdx.x >> 5;                  // 0..7
    int d0 = blockIdx.x * 32, k0 = blockIdx.y * 32;
#pragma unroll
    for (int i = 0; i < 32; i += 8)
        tile[ty + i][tx] = in[(size_t)(k0 + ty + i) * D + d0 + tx];
    __syncthreads();
#pragma unroll
    for (int i = 0; i < 32; i += 8)
        out[(size_t)(d0 + ty + i) * K + k0 + tx] = f2h_bits(tile[tx][ty + i]);
}

// ---------------------------------------------------------------------------
// 128x128-tile GEMM, BK=32, 256 threads (4 waves 2x2), 32x32x16 f16 MFMA.
// A [M,K] fp16 row-major, Bt [N,K] fp16 row-major (i.e. B transposed).
//
// LDS "chunk" layout (verified r2-r4: SQ_LDS_BANK_CONFLICT = 0): chunk
// (rt, ks) holds at lane L's slot the 32x32x16 MFMA fragment pattern, so
// fragment loads are conflict-free ds_read_b128.
//
// XCD-banded 1D grid (verified r3/r4: FETCH at compulsory minimum).
//
// 3-buffer ring + raw-asm barrier (NEW, r5): prefetch runs 2 slabs ahead;
// the per-iter barrier is `s_waitcnt vmcnt(4) lgkmcnt(0); s_barrier` so the
// NEXT slab's 4 gl_lds stay in flight across the barrier (a __syncthreads
// would force vmcnt(0) and re-create the m97 drain stall). Landing window
// = 2 iterations ~ HBM latency. LDS 48 KB -> 3 blocks/CU.
//
// MODE 0: C[M,N] = A@B + bias   (fp16 out)
// MODE 1: Lacc[row] += sum_col (A@B + bias - Xref)^2   (atomic per row)
template <int MODE>
__global__ __launch_bounds__(256) void gemm_bt(
    const u16* __restrict__ A, const u16* __restrict__ Bt,
    const float* __restrict__ bias,
    u16* __restrict__ C, const _Float16* __restrict__ Xref,
    float* __restrict__ Lacc,
    int M, int N, int K, int NT, int P) {
    __shared__ __align__(16) u16 As[3][128 * 32];   // 3 x 8 KB
    __shared__ __align__(16) u16 Bs[3][128 * 32];   // 3 x 8 KB

    const int tid  = threadIdx.x;
    const int lane = tid & 63;
    const int w    = tid >> 6;
    const int wr   = w >> 1, wc = w & 1;
    const int l31 = lane & 31, h = lane >> 5;

    // ---- XCD-banded tile decode ----
    const int b    = blockIdx.x;
    const int xcd  = b & 7;
    const int slot = b >> 3;
    const int perPanel = NT * P;
    const int p    = slot / perPanel;
    const int rem  = slot - p * perPanel;
    const int n_t  = rem / P;
    const int mi   = rem - n_t * P;
    const int mPerX = (M >> 7) >> 3;               // (M/128)/8
    const int m0 = (xcd * mPerX + p * P + mi) * 128;
    const int n0 = n_t * 128;

    f32x16 acc[2][2] = {};

    // staging: 16 chunks of 1KB per BK=32 slab; wave w stages chunks w*4..w*4+3
    const u16* gsrc[4];
    int loff[4];        // chunk offset within As[buf]/Bs[buf] (halfs)
    bool isA[4];
#pragma unroll
    for (int cc = 0; cc < 4; ++cc) {
        int c = w * 4 + cc;                        // wave-uniform
        int ci = c & 7;
        int rt = ci >> 1, ks = ci & 1;
        int row = rt * 32 + l31;
        int ko  = ks * 16 + h * 8;
        isA[cc] = (c < 8);
        if (c < 8) gsrc[cc] = A  + (size_t)(m0 + row) * K + ko;
        else       gsrc[cc] = Bt + (size_t)(n0 + row) * K + ko;
        loff[cc] = (rt * 2 + ks) * 512;
    }

    const int nIter = K >> 5;                      // >= 32 here

    // pre-issue slabs 0 and 1 into buffers 0 and 1
#pragma unroll
    for (int cc = 0; cc < 4; ++cc)
        gl_lds16(gsrc[cc], (isA[cc] ? &As[0][loff[cc]] : &Bs[0][loff[cc]]));
#pragma unroll
    for (int cc = 0; cc < 4; ++cc)
        gl_lds16(gsrc[cc] + 32, (isA[cc] ? &As[1][loff[cc]] : &Bs[1][loff[cc]]));

    int bi = 0;                                    // ring index: buffer of slab `it`
    for (int it = 0; it < nIter - 1; ++it) {
        // wait for slab `it` only (4 newest loads — slab it+1 — stay in flight)
        asm volatile("s_waitcnt vmcnt(4) lgkmcnt(0)\n\ts_barrier" ::: "memory");
        if (it + 2 < nIter) {
            int nb = bi + 2; if (nb >= 3) nb -= 3;   // == buffer of slab it-1
            int kt = (it + 2) << 5;
#pragma unroll
            for (int cc = 0; cc < 4; ++cc)
                gl_lds16(gsrc[cc] + kt,
                         (isA[cc] ? &As[nb][loff[cc]] : &Bs[nb][loff[cc]]));
        }
#pragma unroll
        for (int ks = 0; ks < 2; ++ks) {
            half8 af[2], bf[2];
#pragma unroll
            for (int i = 0; i < 2; ++i) {
                af[i] = *(const half8*)&As[bi][((wr * 2 + i) * 2 + ks) * 512 + lane * 8];
                bf[i] = *(const half8*)&Bs[bi][((wc * 2 + i) * 2 + ks) * 512 + lane * 8];
            }
#pragma unroll
            for (int i = 0; i < 2; ++i)
#pragma unroll
                for (int j = 0; j < 2; ++j)
                    acc[i][j] = __builtin_amdgcn_mfma_f32_32x32x16_f16(
                        af[i], bf[j], acc[i][j], 0, 0, 0);
        }
        ++bi; if (bi >= 3) bi = 0;
    }
    // final slab: full drain
    asm volatile("s_waitcnt vmcnt(0) lgkmcnt(0)\n\ts_barrier" ::: "memory");
#pragma unroll
    for (int ks = 0; ks < 2; ++ks) {
        half8 af[2], bf[2];
#pragma unroll
        for (int i = 0; i < 2; ++i) {
            af[i] = *(const half8*)&As[bi][((wr * 2 + i) * 2 + ks) * 512 + lane * 8];
            bf[i] = *(const half8*)&Bs[bi][((wc * 2 + i) * 2 + ks) * 512 + lane * 8];
        }
#pragma unroll
        for (int i = 0; i < 2; ++i)
#pragma unroll
            for (int j = 0; j < 2; ++j)
                acc[i][j] = __builtin_amdgcn_mfma_f32_32x32x16_f16(
                    af[i], bf[j], acc[i][j], 0, 0, 0);
    }

    // epilogue: 32x32 C/D layout col = lane&31, row = (r&3) + 8*(r>>2) + 4*h
    const int colb = n0 + wc * 64 + l31;
    float bj0 = bias[colb], bj1 = bias[colb + 32];

    if (MODE == 0) {
#pragma unroll
        for (int i = 0; i < 2; ++i) {
            int rowb = m0 + wr * 64 + i * 32 + 4 * h;
#pragma unroll
            for (int r = 0; r < 16; ++r) {
                int row = rowb + (r & 3) + 8 * (r >> 2);
                size_t ro = (size_t)row * N + colb;
                C[ro]      = f2h_bits(acc[i][0][r] + bj0);
                C[ro + 32] = f2h_bits(acc[i][1][r] + bj1);
            }
        }
    } else {
#pragma unroll
        for (int i = 0; i < 2; ++i) {
            int rowb = m0 + wr * 64 + i * 32 + 4 * h;
#pragma unroll
            for (int r = 0; r < 16; ++r) {
                int row = rowb + (r & 3) + 8 * (r >> 2);
                size_t ro = (size_t)row * N + colb;
                float d0 = acc[i][0][r] + bj0 - (float)Xref[ro];
                float d1 = acc[i][1][r] + bj1 - (float)Xref[ro + 32];
                float s = d0 * d0 + d1 * d1;
                // reduce over the 32 lanes (cols) sharing this row
                s += __shfl_xor(s, 1, 64);
                s += __shfl_xor(s, 2, 64);
                s += __shfl_xor(s, 4, 64);
                s += __shfl_xor(s, 8, 64);
                s += __shfl_xor(s, 16, 64);
                if (l31 == 0) atomicAdd(&Lacc[row], s);
            }
        }
    }
}

// ---------------------------------------------------------------------------
// Per-row L3 = sum (h1-h2)^2 and L4row = sum (h1+h2)*whoW. One block per row.
__global__ __launch_bounds__(256) void l34_kernel(
    const u16* __restrict__ H1, const u16* __restrict__ H2,
    const float* __restrict__ whoW,
    float* __restrict__ L3, float* __restrict__ L4) {
    int row = blockIdx.x;
    int tid = threadIdx.x;
    const half8 h1 = *(const half8*)&H1[(size_t)row * DH + tid * 8];
    const half8 h2 = *(const half8*)&H2[(size_t)row * DH + tid * 8];
    float4 w0 = *(const float4*)&whoW[tid * 8];
    float4 w1 = *(const float4*)&whoW[tid * 8 + 4];
    float wv[8] = { w0.x, w0.y, w0.z, w0.w, w1.x, w1.y, w1.z, w1.w };
    float s3 = 0.f, s4 = 0.f;
#pragma unroll
    for (int u = 0; u < 8; ++u) {
        float a = (float)h1[u], b = (float)h2[u];
        float d = a - b;
        s3 += d * d;
        s4 += (a + b) * wv[u];
    }
#pragma unroll
    for (int off = 1; off < 64; off <<= 1) {
        s3 += __shfl_xor(s3, off, 64);
        s4 += __shfl_xor(s4, off, 64);
    }
    __shared__ float sm[8];
    int wvi = tid >> 6, ln = tid & 63;
    if (ln == 0) { sm[wvi] = s3; sm[4 + wvi] = s4; }
    __syncthreads();
    if (tid == 0) {
        L3[row] = sm[0] + sm[1] + sm[2] + sm[3];
        L4[row] = sm[4] + sm[5] + sm[6] + sm[7];
    }
}

// ---------------------------------------------------------------------------
// loss = sum_r L1^2 + L2^2 + L3^2 + (0.5*(L4row + who_b) - Y)^2
__global__ __launch_bounds__(1024) void final_reduce(
    const float* __restrict__ L1, const float* __restrict__ L2,
    const float* __restrict__ L3, const float* __restrict__ L4,
    const float* __restrict__ Y, const float* __restrict__ whob,
    float* __restrict__ out) {
    float s = 0.f;
    float wb = whob[0];
    for (int r = threadIdx.x; r < NR; r += 1024) {
        float l4 = 0.5f * (L4[r] + wb) - Y[r];
        s += L1[r] * L1[r] + L2[r] * L2[r] + L3[r] * L3[r] + l4 * l4;
    }
#pragma unroll
    for (int off = 1; off < 64; off <<= 1) s += __shfl_xor(s, off, 64);
    __shared__ float sm[16];
    int w = threadIdx.x >> 6, ln = threadIdx.x & 63;
    if (ln == 0) sm[w] = s;
    __syncthreads();
    if (threadIdx.x == 0) {
        float t = 0.f;
#pragma unroll
        for (int i = 0; i < 16; ++i) t += sm[i];
        out[0] = t;
    }
}

// ---------------------------------------------------------------------------
extern "C" void kernel_launch(void* const* d_in, const int* in_sizes, int n_in,
                              void* d_out, int out_size, void* d_ws, size_t ws_size,
                              hipStream_t stream) {
    const float* X1   = (const float*)d_in[0];
    const float* X2   = (const float*)d_in[1];
    const float* Y    = (const float*)d_in[2];
    const float* w1hW = (const float*)d_in[3];
    const float* w1hb = (const float*)d_in[4];
    const float* w2hW = (const float*)d_in[5];
    const float* w2hb = (const float*)d_in[6];
    const float* wh1W = (const float*)d_in[7];
    const float* wh1b = (const float*)d_in[8];
    const float* wh2W = (const float*)d_in[9];
    const float* wh2b = (const float*)d_in[10];
    const float* whoW = (const float*)d_in[11];
    const float* whob = (const float*)d_in[12];

    // workspace layout (~208.3 MB total)
    char* ws = (char*)d_ws;
    u16* X1h  = (u16*)(ws);                               // 16384x1024 fp16
    u16* X2h  = X1h + (size_t)NR * DX;
    u16* H1h  = X2h + (size_t)NR * DX;                    // 16384x2048 fp16
    u16* H2h  = H1h + (size_t)NR * DH;
    u16* w1hT = H2h + (size_t)NR * DH;                    // [DH][DX]
    u16* w2hT = w1hT + (size_t)DH * DX;
    u16* wh1T = w2hT + (size_t)DH * DX;                   // [DX][DH]
    u16* wh2T = wh1T + (size_t)DX * DH;
    float* L1a = (float*)(wh2T + (size_t)DX * DH);        // 4 x 16384 f32
    float* L2a = L1a + NR;
    float* L3a = L2a + NR;
    float* L4a = L3a + NR;

    // zero the atomically-accumulated arrays (ws is poisoned 0xAA each call)
    hipMemsetAsync(L1a, 0, 2 * (size_t)NR * sizeof(float), stream);

    // casts
    cast_f32_f16<<<NR * DX / 1024, 256, 0, stream>>>(X1, X1h);
    cast_f32_f16<<<NR * DX / 1024, 256, 0, stream>>>(X2, X2h);
    transpose_cast<<<dim3(DH / 32, DX / 32), 256, 0, stream>>>(w1hW, w1hT, DX, DH);
    transpose_cast<<<dim3(DH / 32, DX / 32), 256, 0, stream>>>(w2hW, w2hT, DX, DH);
    transpose_cast<<<dim3(DX / 32, DH / 32), 256, 0, stream>>>(wh1W, wh1T, DH, DX);
    transpose_cast<<<dim3(DX / 32, DH / 32), 256, 0, stream>>>(wh2W, wh2T, DH, DX);

    // H1 = X1@w1h + b, H2 = X2@w2h + b  (fp16 out). K=1024 -> panel P=8.
    gemm_bt<0><<<(NR / 128) * (DH / 128), 256, 0, stream>>>(
        X1h, w1hT, w1hb, H1h, nullptr, nullptr, NR, DH, DX, DH / 128, 8);
    gemm_bt<0><<<(NR / 128) * (DH / 128), 256, 0, stream>>>(
        X2h, w2hT, w2hb, H2h, nullptr, nullptr, NR, DH, DX, DH / 128, 8);

    // L3, L4row from H1, H2
    l34_kernel<<<NR, 256, 0, stream>>>(H1h, H2h, whoW, L3a, L4a);

    // L1 = rowsq(H1@wh2 + b - X2), L2 = rowsq(H2@wh1 + b - X1). K=2048 -> P=4.
    gemm_bt<1><<<(NR / 128) * (DX / 128), 256, 0, stream>>>(
        H1h, wh2T, wh2b, nullptr, (const _Float16*)X2h, L1a, NR, DX, DH, DX / 128, 4);
    gemm_bt<1><<<(NR / 128) * (DX / 128), 256, 0, stream>>>(
        H2h, wh1T, wh1b, nullptr, (const _Float16*)X1h, L2a, NR, DX, DH, DX / 128, 4);

    final_reduce<<<1, 1024, 0, stream>>>(L1a, L2a, L3a, L4a, Y, whob, (float*)d_out);
}